// Round 9
// baseline (118.751 us; speedup 1.0000x reference)
//
#include <hip/hip_runtime.h>
#include <math.h>

#define NA_ 128
#define F_ 256
#define VBS_ 128
#define GAMMA_ 1.5f
#define EPS_ 1e-5f

typedef __attribute__((ext_vector_type(8))) short short8;
typedef __attribute__((ext_vector_type(4))) float f32x4;

static __device__ __forceinline__ unsigned f2bf(float f) {
    unsigned u = __float_as_uint(f);
    return (u + 0x7FFFu + ((u >> 16) & 1u)) >> 16;   // RNE bf16
}
static __device__ __forceinline__ float bflo(unsigned u) { return __uint_as_float(u << 16); }
static __device__ __forceinline__ float bfhi(unsigned u) { return __uint_as_float(u & 0xFFFF0000u); }

// DPP lane-move: dest lanes without a source get `old` (bound_ctrl=false)
template <int C>
static __device__ __forceinline__ float dpp_mov(float v, float old) {
    return __builtin_bit_cast(float, __builtin_amdgcn_update_dpp(
        __builtin_bit_cast(int, old), __builtin_bit_cast(int, v), C, 0xF, 0xF, false));
}

// faithful sorted sparsemax tau (rare/never slow path), wave-uniform entry
static __device__ __forceinline__ float slow_tau(float z0, float z1, float z2, float z3,
                                                 float* sr, int lane) {
    sr[4 * lane + 0] = z0; sr[4 * lane + 1] = z1;
    sr[4 * lane + 2] = z2; sr[4 * lane + 3] = z3;
    __asm__ volatile("s_waitcnt lgkmcnt(0)" ::: "memory");
    float t0 = 0.f;
    if (lane == 0) {
        for (int i = 1; i < F_; ++i) {             // insertion sort ascending
            float key = sr[i]; int j = i - 1;
            while (j >= 0 && sr[j] > key) { sr[j + 1] = sr[j]; --j; }
            sr[j + 1] = key;
        }
        float cs = 0.f; int kz = 0;
        for (int j = 0; j < F_; ++j) {
            cs += sr[j];
            if (1.0f + (float)j * sr[j] - cs > 0.0f) kz = j;
        }
        float mz = 0.f;
        for (int j = 0; j <= kz; ++j) mz += sr[j];
        t0 = (mz + 1.0f) / (float)kz;              // kz==0 -> inf -> m=0 (matches clip)
    }
    return __shfl(t0, 0, 64);
}

// ---------------- kernel 0: W f32 -> bf16 (64 KB, one-time) ----------------
__global__ void k0_cvt_w(const float* __restrict__ W, unsigned short* __restrict__ Wb) {
    int i = blockIdx.x * 256 + threadIdx.x;          // 8192 groups of 4
    float4 v = reinterpret_cast<const float4*>(W)[i];
    uint2 o;
    o.x = f2bf(v.x) | (f2bf(v.y) << 16);
    o.y = f2bf(v.z) | (f2bf(v.w) << 16);
    reinterpret_cast<uint2*>(Wb)[i] = o;
}

// ---------------- fully fused: GEMM + ghost-BN + sparsemax + outputs ----------------
// block = one virtual-batch chunk (128 rows), 512 threads = 8 waves (2 row-halves x 4 col-quarters)
// NEW: L2-warm prefetch of the whole prior chunk during the compute phases (convoy-breaker).
__global__ __launch_bounds__(512, 4) void k_fused(
    const float* __restrict__ a, const unsigned short* __restrict__ Wb,
    const float* __restrict__ bnw, const float* __restrict__ bnb,
    const float* __restrict__ prior,
    float* __restrict__ out_m, float* __restrict__ out_np)
{
    // zlds: column-major znorm, 256 cols x 32 row-groups (4 rows bf16 packed per 8B qword) = 64 KB.
    // qword slot(col, rg) = (rg ^ (col&31) ^ ((col>>2)&31)) & 31
    __shared__ unsigned long long zlds[F_ * 32];
    __shared__ float sbuf[2][4][4][16];            // BN partial sums  [wr][wc][ft][lr]
    __shared__ float qbuf[2][4][4][16];            // BN partial sumsq
    __shared__ float zrow[8][F_];                  // per-wave slow-path sort buffer

    unsigned short* albuf = reinterpret_cast<unsigned short*>(zlds);  // first 32 KB: A-tile

    const int tid = threadIdx.x;
    const int lane = tid & 63, wid = tid >> 6;
    const int wr = wid >> 2, wc = wid & 3;         // wave = (row-half, col-quarter)
    const int lr = lane & 15, lg = lane >> 4;
    const size_t rowbase = (size_t)blockIdx.x * VBS_;

    // ---- stage a (f32) -> bf16 LDS (A-tile region), swizzle byte ^= ((row&7)<<4)
    #pragma unroll
    for (int i = 0; i < 4; ++i) {
        int seg = tid + 512 * i;                   // 2048 segs of 8 elems
        int row = seg >> 4, ks = seg & 15;
        const float4* g = reinterpret_cast<const float4*>(a + (rowbase + row) * NA_ + ks * 8);
        float4 v0 = g[0], v1 = g[1];
        uint4 pk;
        pk.x = f2bf(v0.x) | (f2bf(v0.y) << 16);
        pk.y = f2bf(v0.z) | (f2bf(v0.w) << 16);
        pk.z = f2bf(v1.x) | (f2bf(v1.y) << 16);
        pk.w = f2bf(v1.z) | (f2bf(v1.w) << 16);
        int byte = (row * 256 + ks * 16) ^ ((row & 7) << 4);
        *reinterpret_cast<uint4*>(reinterpret_cast<char*>(albuf) + byte) = pk;
    }
    __syncthreads();

    // ---- L2-warm prefetch: touch every 128B line of this chunk's prior slab (128 KB).
    // Completes during MFMA+BN; epilogue prior reads become L2 hits. Pinned live (no DCE).
    {
        const float* pf = prior + rowbase * F_;
        float t0 = pf[tid * 32];                   // 512 touches x 128B
        float t1 = pf[16384 + tid * 32];           // remaining 64 KB
        __asm__ volatile("" :: "v"(t0), "v"(t1));
    }

    // ---- MFMA: wave computes rows [wr*64, +64) x cols [wc*64, +64)
    f32x4 acc[4][4];
    #pragma unroll
    for (int m = 0; m < 4; ++m)
        #pragma unroll
        for (int ft = 0; ft < 4; ++ft)
            acc[m][ft] = (f32x4){0.f, 0.f, 0.f, 0.f};

    // linear bias b cancels through BN -> skipped
    #pragma unroll
    for (int kt = 0; kt < 4; ++kt) {
        short8 bfr[4];
        #pragma unroll
        for (int ft = 0; ft < 4; ++ft)   // B-frag: col = lr, k = kt*32 + lg*8 + j
            bfr[ft] = *reinterpret_cast<const short8*>(
                Wb + (size_t)(wc * 64 + ft * 16 + lr) * NA_ + kt * 32 + lg * 8);
        #pragma unroll
        for (int m = 0; m < 4; ++m) {
            int row = wr * 64 + m * 16 + lr;       // A-frag: row = lr, k = kt*32 + lg*8 + j
            int byte = (row * 256 + kt * 64 + lg * 16) ^ ((row & 7) << 4);
            short8 afr = *reinterpret_cast<const short8*>(
                reinterpret_cast<const char*>(albuf) + byte);
            #pragma unroll
            for (int ft = 0; ft < 4; ++ft)
                acc[m][ft] = __builtin_amdgcn_mfma_f32_16x16x32_bf16(afr, bfr[ft], acc[m][ft], 0, 0, 0);
        }
    }

    // ---- BN stats: intra-wave 64-row partials, cross-wr via LDS
    #pragma unroll
    for (int ft = 0; ft < 4; ++ft) {
        float s = 0.f, q = 0.f;
        #pragma unroll
        for (int m = 0; m < 4; ++m)
            #pragma unroll
            for (int r = 0; r < 4; ++r) {
                float v = acc[m][ft][r];
                s += v; q = fmaf(v, v, q);
            }
        s += __shfl_xor(s, 16, 64); s += __shfl_xor(s, 32, 64);
        q += __shfl_xor(q, 16, 64); q += __shfl_xor(q, 32, 64);
        if (lg == 0) { sbuf[wr][wc][ft][lr] = s; qbuf[wr][wc][ft][lr] = q; }
    }
    __syncthreads();   // also guarantees all A-tile reads done before zlds overwrite

    float rs[4], sh[4];
    #pragma unroll
    for (int ft = 0; ft < 4; ++ft) {
        float s = sbuf[0][wc][ft][lr] + sbuf[1][wc][ft][lr];
        float q = qbuf[0][wc][ft][lr] + qbuf[1][wc][ft][lr];
        int f = wc * 64 + ft * 16 + lr;
        float mean = s * (1.f / VBS_);
        float var  = q * (1.f / VBS_) - mean * mean;
        rs[ft] = rsqrtf(var + EPS_) * bnw[f];
        sh[ft] = fmaf(-mean, rs[ft], bnb[f]);
    }

    // ---- BN-apply; pack 4 rows bf16 -> column-major swizzled zlds (b64 writes)
    #pragma unroll
    for (int m = 0; m < 4; ++m) {
        int rg = wr * 16 + m * 4 + lg;             // row-group = rows [rg*4, rg*4+4)
        #pragma unroll
        for (int ft = 0; ft < 4; ++ft) {
            int col = wc * 64 + ft * 16 + lr;
            uint2 zk;
            zk.x = f2bf(fmaf(acc[m][ft][0], rs[ft], sh[ft]))
                 | (f2bf(fmaf(acc[m][ft][1], rs[ft], sh[ft])) << 16);
            zk.y = f2bf(fmaf(acc[m][ft][2], rs[ft], sh[ft]))
                 | (f2bf(fmaf(acc[m][ft][3], rs[ft], sh[ft])) << 16);
            int slot = (rg ^ (col & 31) ^ ((col >> 2) & 31)) & 31;
            zlds[col * 32 + slot] = *reinterpret_cast<unsigned long long*>(&zk);
        }
    }

    // ---- prefetch prior for this wave's first row-group (in flight across the barrier)
    const int rg0 = wid * 4;                       // wave owns row-groups rg0..rg0+3 (16 rows)
    float4 pn0, pn1, pn2, pn3;
    {
        const float* pb = prior + (rowbase + rg0 * 4) * F_;
        pn0 = reinterpret_cast<const float4*>(pb)[lane];
        pn1 = reinterpret_cast<const float4*>(pb + F_)[lane];
        pn2 = reinterpret_cast<const float4*>(pb + 2 * F_)[lane];
        pn3 = reinterpret_cast<const float4*>(pb + 3 * F_)[lane];
    }
    __syncthreads();

    // ---- epilogue: 4 rows per iteration
    const int l31 = lane & 31;
    #pragma unroll
    for (int g = 0; g < 4; ++g) {
        const int rg = rg0 + g;
        float4 p0 = pn0, p1 = pn1, p2 = pn2, p3 = pn3;
        if (g < 3) {
            const float* pb = prior + (rowbase + (rg + 1) * 4) * F_;
            pn0 = reinterpret_cast<const float4*>(pb)[lane];
            pn1 = reinterpret_cast<const float4*>(pb + F_)[lane];
            pn2 = reinterpret_cast<const float4*>(pb + 2 * F_)[lane];
            pn3 = reinterpret_cast<const float4*>(pb + 3 * F_)[lane];
        }

        // one qword per owned column: 4 rows packed
        uint2 q[4];
        #pragma unroll
        for (int c = 0; c < 4; ++c) {
            int col = 4 * lane + c;
            int slot = (rg ^ (col & 31) ^ l31) & 31;
            q[c] = *reinterpret_cast<const uint2*>(
                reinterpret_cast<const char*>(zlds) + col * 256 + slot * 8);
        }

        // z[r][c] = znorm_bf16(row rg*4+r, col 4*lane+c) * prior
        float zr0[4], zr1[4], zr2[4], zr3[4];
        float pv0[4] = {p0.x, p0.y, p0.z, p0.w};
        float pv1[4] = {p1.x, p1.y, p1.z, p1.w};
        float pv2[4] = {p2.x, p2.y, p2.z, p2.w};
        float pv3[4] = {p3.x, p3.y, p3.z, p3.w};
        #pragma unroll
        for (int c = 0; c < 4; ++c) {
            zr0[c] = bflo(q[c].x) * pv0[c];
            zr1[c] = bfhi(q[c].x) * pv1[c];
            zr2[c] = bflo(q[c].y) * pv2[c];
            zr3[c] = bfhi(q[c].y) * pv3[c];
        }

        // 4 interleaved DPP reduction chains (sum + max), lane 63 holds totals
        float s0 = (zr0[0] + zr0[1]) + (zr0[2] + zr0[3]);
        float s1 = (zr1[0] + zr1[1]) + (zr1[2] + zr1[3]);
        float s2 = (zr2[0] + zr2[1]) + (zr2[2] + zr2[3]);
        float s3 = (zr3[0] + zr3[1]) + (zr3[2] + zr3[3]);
        float x0 = fmaxf(fmaxf(zr0[0], zr0[1]), fmaxf(zr0[2], zr0[3]));
        float x1 = fmaxf(fmaxf(zr1[0], zr1[1]), fmaxf(zr1[2], zr1[3]));
        float x2 = fmaxf(fmaxf(zr2[0], zr2[1]), fmaxf(zr2[2], zr2[3]));
        float x3 = fmaxf(fmaxf(zr3[0], zr3[1]), fmaxf(zr3[2], zr3[3]));
        #define RSTEP(C) \
            s0 += dpp_mov<C>(s0, 0.f); s1 += dpp_mov<C>(s1, 0.f); \
            s2 += dpp_mov<C>(s2, 0.f); s3 += dpp_mov<C>(s3, 0.f); \
            x0 = fmaxf(x0, dpp_mov<C>(x0, x0)); x1 = fmaxf(x1, dpp_mov<C>(x1, x1)); \
            x2 = fmaxf(x2, dpp_mov<C>(x2, x2)); x3 = fmaxf(x3, dpp_mov<C>(x3, x3));
        RSTEP(0xB1)   // quad_perm [1,0,3,2]
        RSTEP(0x4E)   // quad_perm [2,3,0,1]
        RSTEP(0x141)  // row_half_mirror
        RSTEP(0x140)  // row_mirror
        RSTEP(0x142)  // row_bcast15
        RSTEP(0x143)  // row_bcast31
        #undef RSTEP
        float S0 = __builtin_bit_cast(float, __builtin_amdgcn_readlane(__builtin_bit_cast(int, s0), 63));
        float S1 = __builtin_bit_cast(float, __builtin_amdgcn_readlane(__builtin_bit_cast(int, s1), 63));
        float S2 = __builtin_bit_cast(float, __builtin_amdgcn_readlane(__builtin_bit_cast(int, s2), 63));
        float S3 = __builtin_bit_cast(float, __builtin_amdgcn_readlane(__builtin_bit_cast(int, s3), 63));
        float X0 = __builtin_bit_cast(float, __builtin_amdgcn_readlane(__builtin_bit_cast(int, x0), 63));
        float X1 = __builtin_bit_cast(float, __builtin_amdgcn_readlane(__builtin_bit_cast(int, x1), 63));
        float X2 = __builtin_bit_cast(float, __builtin_amdgcn_readlane(__builtin_bit_cast(int, x2), 63));
        float X3 = __builtin_bit_cast(float, __builtin_amdgcn_readlane(__builtin_bit_cast(int, x3), 63));

        // fast path: w[255] true -> k_z = 255, m_z = full sum (~always for BN'd data)
        float t0 = (S0 + 1.0f) * (1.0f / 255.0f);
        float t1 = (S1 + 1.0f) * (1.0f / 255.0f);
        float t2 = (S2 + 1.0f) * (1.0f / 255.0f);
        float t3 = (S3 + 1.0f) * (1.0f / 255.0f);
        bool b0 = !(1.0f + 255.0f * X0 - S0 > 0.0f);
        bool b1 = !(1.0f + 255.0f * X1 - S1 > 0.0f);
        bool b2 = !(1.0f + 255.0f * X2 - S2 > 0.0f);
        bool b3 = !(1.0f + 255.0f * X3 - S3 > 0.0f);
        if (b0 | b1 | b2 | b3) {                   // wave-uniform (S,X are wave-uniform)
            float* sr = zrow[wid];
            if (b0) t0 = slow_tau(zr0[0], zr0[1], zr0[2], zr0[3], sr, lane);
            if (b1) t1 = slow_tau(zr1[0], zr1[1], zr1[2], zr1[3], sr, lane);
            if (b2) t2 = slow_tau(zr2[0], zr2[1], zr2[2], zr2[3], sr, lane);
            if (b3) t3 = slow_tau(zr3[0], zr3[1], zr3[2], zr3[3], sr, lane);
        }

        // outputs: m = relu(z - tau); new_prior = p * (1.5 - m)
        size_t gb = (rowbase + rg * 4) * F_;
        {
            float m0 = fmaxf(zr0[0] - t0, 0.f), m1 = fmaxf(zr0[1] - t0, 0.f);
            float m2 = fmaxf(zr0[2] - t0, 0.f), m3 = fmaxf(zr0[3] - t0, 0.f);
            float4 om = {m0, m1, m2, m3};
            float4 on = {pv0[0] * (GAMMA_ - m0), pv0[1] * (GAMMA_ - m1),
                         pv0[2] * (GAMMA_ - m2), pv0[3] * (GAMMA_ - m3)};
            reinterpret_cast<float4*>(out_m  + gb)[lane] = om;
            reinterpret_cast<float4*>(out_np + gb)[lane] = on;
        }
        {
            float m0 = fmaxf(zr1[0] - t1, 0.f), m1 = fmaxf(zr1[1] - t1, 0.f);
            float m2 = fmaxf(zr1[2] - t1, 0.f), m3 = fmaxf(zr1[3] - t1, 0.f);
            float4 om = {m0, m1, m2, m3};
            float4 on = {pv1[0] * (GAMMA_ - m0), pv1[1] * (GAMMA_ - m1),
                         pv1[2] * (GAMMA_ - m2), pv1[3] * (GAMMA_ - m3)};
            reinterpret_cast<float4*>(out_m  + gb + F_)[lane] = om;
            reinterpret_cast<float4*>(out_np + gb + F_)[lane] = on;
        }
        {
            float m0 = fmaxf(zr2[0] - t2, 0.f), m1 = fmaxf(zr2[1] - t2, 0.f);
            float m2 = fmaxf(zr2[2] - t2, 0.f), m3 = fmaxf(zr2[3] - t2, 0.f);
            float4 om = {m0, m1, m2, m3};
            float4 on = {pv2[0] * (GAMMA_ - m0), pv2[1] * (GAMMA_ - m1),
                         pv2[2] * (GAMMA_ - m2), pv2[3] * (GAMMA_ - m3)};
            reinterpret_cast<float4*>(out_m  + gb + 2 * F_)[lane] = om;
            reinterpret_cast<float4*>(out_np + gb + 2 * F_)[lane] = on;
        }
        {
            float m0 = fmaxf(zr3[0] - t3, 0.f), m1 = fmaxf(zr3[1] - t3, 0.f);
            float m2 = fmaxf(zr3[2] - t3, 0.f), m3 = fmaxf(zr3[3] - t3, 0.f);
            float4 om = {m0, m1, m2, m3};
            float4 on = {pv3[0] * (GAMMA_ - m0), pv3[1] * (GAMMA_ - m1),
                         pv3[2] * (GAMMA_ - m2), pv3[3] * (GAMMA_ - m3)};
            reinterpret_cast<float4*>(out_m  + gb + 3 * F_)[lane] = om;
            reinterpret_cast<float4*>(out_np + gb + 3 * F_)[lane] = on;
        }
    }
}

extern "C" void kernel_launch(void* const* d_in, const int* in_sizes, int n_in,
                              void* d_out, int out_size, void* d_ws, size_t ws_size,
                              hipStream_t stream) {
    const float* a     = (const float*)d_in[0];
    const float* prior = (const float*)d_in[1];
    const float* W     = (const float*)d_in[2];
    const float* bnw   = (const float*)d_in[4];
    const float* bnb   = (const float*)d_in[5];
    const int N = in_sizes[0] / NA_;
    const int nchunks = N / VBS_;
    float* out_m  = (float*)d_out;
    float* out_np = out_m + (size_t)N * F_;

    unsigned short* Wb = (unsigned short*)d_ws;    // 64 KB in workspace
    k0_cvt_w<<<(F_ * NA_ / 4 + 255) / 256, 256, 0, stream>>>(W, Wb);
    k_fused<<<nchunks, 512, 0, stream>>>(a, Wb, bnw, bnb, prior, out_m, out_np);
}

// Round 10
// 104.296 us; speedup vs baseline: 1.1386x; 1.1386x over previous
//
#include <hip/hip_runtime.h>
#include <math.h>

#define NA_ 128
#define F_ 256
#define VBS_ 128
#define GAMMA_ 1.5f
#define EPS_ 1e-5f

typedef __attribute__((ext_vector_type(8))) short short8;
typedef __attribute__((ext_vector_type(4))) float f32x4;

static __device__ __forceinline__ unsigned f2bf(float f) {
    unsigned u = __float_as_uint(f);
    return (u + 0x7FFFu + ((u >> 16) & 1u)) >> 16;   // RNE bf16
}
static __device__ __forceinline__ float bflo(unsigned u) { return __uint_as_float(u << 16); }
static __device__ __forceinline__ float bfhi(unsigned u) { return __uint_as_float(u & 0xFFFF0000u); }

// DPP lane-move: dest lanes without a source get `old` (bound_ctrl=false)
template <int C>
static __device__ __forceinline__ float dpp_mov(float v, float old) {
    return __builtin_bit_cast(float, __builtin_amdgcn_update_dpp(
        __builtin_bit_cast(int, old), __builtin_bit_cast(int, v), C, 0xF, 0xF, false));
}

static __device__ __forceinline__ float4 ntload4(const float* p) {
    float4 v;
    v.x = __builtin_nontemporal_load(p + 0);
    v.y = __builtin_nontemporal_load(p + 1);
    v.z = __builtin_nontemporal_load(p + 2);
    v.w = __builtin_nontemporal_load(p + 3);
    return v;
}
static __device__ __forceinline__ void ntstore4(float* p, float4 v) {
    __builtin_nontemporal_store(v.x, p + 0);
    __builtin_nontemporal_store(v.y, p + 1);
    __builtin_nontemporal_store(v.z, p + 2);
    __builtin_nontemporal_store(v.w, p + 3);
}

// faithful sorted sparsemax tau (rare/never slow path), wave-uniform entry
static __device__ __forceinline__ float slow_tau(float z0, float z1, float z2, float z3,
                                                 float* sr, int lane) {
    sr[4 * lane + 0] = z0; sr[4 * lane + 1] = z1;
    sr[4 * lane + 2] = z2; sr[4 * lane + 3] = z3;
    __asm__ volatile("s_waitcnt lgkmcnt(0)" ::: "memory");
    float t0 = 0.f;
    if (lane == 0) {
        for (int i = 1; i < F_; ++i) {             // insertion sort ascending
            float key = sr[i]; int j = i - 1;
            while (j >= 0 && sr[j] > key) { sr[j + 1] = sr[j]; --j; }
            sr[j + 1] = key;
        }
        float cs = 0.f; int kz = 0;
        for (int j = 0; j < F_; ++j) {
            cs += sr[j];
            if (1.0f + (float)j * sr[j] - cs > 0.0f) kz = j;
        }
        float mz = 0.f;
        for (int j = 0; j <= kz; ++j) mz += sr[j];
        t0 = (mz + 1.0f) / (float)kz;              // kz==0 -> inf -> m=0 (matches clip)
    }
    return __shfl(t0, 0, 64);
}

// ---------------- kernel 0: W f32 -> bf16 (64 KB, one-time) ----------------
__global__ void k0_cvt_w(const float* __restrict__ W, unsigned short* __restrict__ Wb) {
    int i = blockIdx.x * 256 + threadIdx.x;          // 8192 groups of 4
    float4 v = reinterpret_cast<const float4*>(W)[i];
    uint2 o;
    o.x = f2bf(v.x) | (f2bf(v.y) << 16);
    o.y = f2bf(v.z) | (f2bf(v.w) << 16);
    reinterpret_cast<uint2*>(Wb)[i] = o;
}

// ---------------- fully fused: GEMM + ghost-BN + sparsemax + outputs ----------------
// block = one virtual-batch chunk (128 rows), 512 threads = 8 waves (2 row-halves x 4 col-quarters)
// Round-8 structure + nontemporal hints on all streaming global accesses (L2-bypass).
__global__ __launch_bounds__(512, 4) void k_fused(
    const float* __restrict__ a, const unsigned short* __restrict__ Wb,
    const float* __restrict__ bnw, const float* __restrict__ bnb,
    const float* __restrict__ prior,
    float* __restrict__ out_m, float* __restrict__ out_np)
{
    // zlds: column-major znorm, 256 cols x 32 row-groups (4 rows bf16 packed per 8B qword) = 64 KB.
    // qword slot(col, rg) = (rg ^ (col&31) ^ ((col>>2)&31)) & 31
    __shared__ unsigned long long zlds[F_ * 32];
    __shared__ float sbuf[2][4][4][16];            // BN partial sums  [wr][wc][ft][lr]
    __shared__ float qbuf[2][4][4][16];            // BN partial sumsq
    __shared__ float zrow[8][F_];                  // per-wave slow-path sort buffer

    unsigned short* albuf = reinterpret_cast<unsigned short*>(zlds);  // first 32 KB: A-tile

    const int tid = threadIdx.x;
    const int lane = tid & 63, wid = tid >> 6;
    const int wr = wid >> 2, wc = wid & 3;         // wave = (row-half, col-quarter)
    const int lr = lane & 15, lg = lane >> 4;
    const size_t rowbase = (size_t)blockIdx.x * VBS_;

    // ---- stage a (f32) -> bf16 LDS (A-tile region), swizzle byte ^= ((row&7)<<4)
    #pragma unroll
    for (int i = 0; i < 4; ++i) {
        int seg = tid + 512 * i;                   // 2048 segs of 8 elems
        int row = seg >> 4, ks = seg & 15;
        const float* g = a + (rowbase + row) * NA_ + ks * 8;
        float4 v0 = ntload4(g), v1 = ntload4(g + 4);
        uint4 pk;
        pk.x = f2bf(v0.x) | (f2bf(v0.y) << 16);
        pk.y = f2bf(v0.z) | (f2bf(v0.w) << 16);
        pk.z = f2bf(v1.x) | (f2bf(v1.y) << 16);
        pk.w = f2bf(v1.z) | (f2bf(v1.w) << 16);
        int byte = (row * 256 + ks * 16) ^ ((row & 7) << 4);
        *reinterpret_cast<uint4*>(reinterpret_cast<char*>(albuf) + byte) = pk;
    }
    __syncthreads();

    // ---- MFMA: wave computes rows [wr*64, +64) x cols [wc*64, +64)
    f32x4 acc[4][4];
    #pragma unroll
    for (int m = 0; m < 4; ++m)
        #pragma unroll
        for (int ft = 0; ft < 4; ++ft)
            acc[m][ft] = (f32x4){0.f, 0.f, 0.f, 0.f};

    // linear bias b cancels through BN -> skipped
    #pragma unroll
    for (int kt = 0; kt < 4; ++kt) {
        short8 bfr[4];
        #pragma unroll
        for (int ft = 0; ft < 4; ++ft)   // B-frag: col = lr, k = kt*32 + lg*8 + j
            bfr[ft] = *reinterpret_cast<const short8*>(
                Wb + (size_t)(wc * 64 + ft * 16 + lr) * NA_ + kt * 32 + lg * 8);
        #pragma unroll
        for (int m = 0; m < 4; ++m) {
            int row = wr * 64 + m * 16 + lr;       // A-frag: row = lr, k = kt*32 + lg*8 + j
            int byte = (row * 256 + kt * 64 + lg * 16) ^ ((row & 7) << 4);
            short8 afr = *reinterpret_cast<const short8*>(
                reinterpret_cast<const char*>(albuf) + byte);
            #pragma unroll
            for (int ft = 0; ft < 4; ++ft)
                acc[m][ft] = __builtin_amdgcn_mfma_f32_16x16x32_bf16(afr, bfr[ft], acc[m][ft], 0, 0, 0);
        }
    }

    // ---- BN stats: intra-wave 64-row partials, cross-wr via LDS
    #pragma unroll
    for (int ft = 0; ft < 4; ++ft) {
        float s = 0.f, q = 0.f;
        #pragma unroll
        for (int m = 0; m < 4; ++m)
            #pragma unroll
            for (int r = 0; r < 4; ++r) {
                float v = acc[m][ft][r];
                s += v; q = fmaf(v, v, q);
            }
        s += __shfl_xor(s, 16, 64); s += __shfl_xor(s, 32, 64);
        q += __shfl_xor(q, 16, 64); q += __shfl_xor(q, 32, 64);
        if (lg == 0) { sbuf[wr][wc][ft][lr] = s; qbuf[wr][wc][ft][lr] = q; }
    }
    __syncthreads();   // also guarantees all A-tile reads done before zlds overwrite

    float rs[4], sh[4];
    #pragma unroll
    for (int ft = 0; ft < 4; ++ft) {
        float s = sbuf[0][wc][ft][lr] + sbuf[1][wc][ft][lr];
        float q = qbuf[0][wc][ft][lr] + qbuf[1][wc][ft][lr];
        int f = wc * 64 + ft * 16 + lr;
        float mean = s * (1.f / VBS_);
        float var  = q * (1.f / VBS_) - mean * mean;
        rs[ft] = rsqrtf(var + EPS_) * bnw[f];
        sh[ft] = fmaf(-mean, rs[ft], bnb[f]);
    }

    // ---- BN-apply; pack 4 rows bf16 -> column-major swizzled zlds (b64 writes)
    #pragma unroll
    for (int m = 0; m < 4; ++m) {
        int rg = wr * 16 + m * 4 + lg;             // row-group = rows [rg*4, rg*4+4)
        #pragma unroll
        for (int ft = 0; ft < 4; ++ft) {
            int col = wc * 64 + ft * 16 + lr;
            uint2 zk;
            zk.x = f2bf(fmaf(acc[m][ft][0], rs[ft], sh[ft]))
                 | (f2bf(fmaf(acc[m][ft][1], rs[ft], sh[ft])) << 16);
            zk.y = f2bf(fmaf(acc[m][ft][2], rs[ft], sh[ft]))
                 | (f2bf(fmaf(acc[m][ft][3], rs[ft], sh[ft])) << 16);
            int slot = (rg ^ (col & 31) ^ ((col >> 2) & 31)) & 31;
            zlds[col * 32 + slot] = *reinterpret_cast<unsigned long long*>(&zk);
        }
    }

    // ---- prefetch prior for this wave's first row-group (in flight across the barrier)
    const int rg0 = wid * 4;                       // wave owns row-groups rg0..rg0+3 (16 rows)
    float4 pn0, pn1, pn2, pn3;
    {
        const float* pb = prior + (rowbase + rg0 * 4) * F_;
        pn0 = ntload4(pb + 4 * lane);
        pn1 = ntload4(pb + F_ + 4 * lane);
        pn2 = ntload4(pb + 2 * F_ + 4 * lane);
        pn3 = ntload4(pb + 3 * F_ + 4 * lane);
    }
    __syncthreads();

    // ---- epilogue: 4 rows per iteration
    const int l31 = lane & 31;
    #pragma unroll
    for (int g = 0; g < 4; ++g) {
        const int rg = rg0 + g;
        float4 p0 = pn0, p1 = pn1, p2 = pn2, p3 = pn3;
        if (g < 3) {
            const float* pb = prior + (rowbase + (rg + 1) * 4) * F_;
            pn0 = ntload4(pb + 4 * lane);
            pn1 = ntload4(pb + F_ + 4 * lane);
            pn2 = ntload4(pb + 2 * F_ + 4 * lane);
            pn3 = ntload4(pb + 3 * F_ + 4 * lane);
        }

        // one qword per owned column: 4 rows packed
        uint2 q[4];
        #pragma unroll
        for (int c = 0; c < 4; ++c) {
            int col = 4 * lane + c;
            int slot = (rg ^ (col & 31) ^ l31) & 31;
            q[c] = *reinterpret_cast<const uint2*>(
                reinterpret_cast<const char*>(zlds) + col * 256 + slot * 8);
        }

        // z[r][c] = znorm_bf16(row rg*4+r, col 4*lane+c) * prior
        float zr0[4], zr1[4], zr2[4], zr3[4];
        float pv0[4] = {p0.x, p0.y, p0.z, p0.w};
        float pv1[4] = {p1.x, p1.y, p1.z, p1.w};
        float pv2[4] = {p2.x, p2.y, p2.z, p2.w};
        float pv3[4] = {p3.x, p3.y, p3.z, p3.w};
        #pragma unroll
        for (int c = 0; c < 4; ++c) {
            zr0[c] = bflo(q[c].x) * pv0[c];
            zr1[c] = bfhi(q[c].x) * pv1[c];
            zr2[c] = bflo(q[c].y) * pv2[c];
            zr3[c] = bfhi(q[c].y) * pv3[c];
        }

        // 4 interleaved DPP reduction chains (sum + max), lane 63 holds totals
        float s0 = (zr0[0] + zr0[1]) + (zr0[2] + zr0[3]);
        float s1 = (zr1[0] + zr1[1]) + (zr1[2] + zr1[3]);
        float s2 = (zr2[0] + zr2[1]) + (zr2[2] + zr2[3]);
        float s3 = (zr3[0] + zr3[1]) + (zr3[2] + zr3[3]);
        float x0 = fmaxf(fmaxf(zr0[0], zr0[1]), fmaxf(zr0[2], zr0[3]));
        float x1 = fmaxf(fmaxf(zr1[0], zr1[1]), fmaxf(zr1[2], zr1[3]));
        float x2 = fmaxf(fmaxf(zr2[0], zr2[1]), fmaxf(zr2[2], zr2[3]));
        float x3 = fmaxf(fmaxf(zr3[0], zr3[1]), fmaxf(zr3[2], zr3[3]));
        #define RSTEP(C) \
            s0 += dpp_mov<C>(s0, 0.f); s1 += dpp_mov<C>(s1, 0.f); \
            s2 += dpp_mov<C>(s2, 0.f); s3 += dpp_mov<C>(s3, 0.f); \
            x0 = fmaxf(x0, dpp_mov<C>(x0, x0)); x1 = fmaxf(x1, dpp_mov<C>(x1, x1)); \
            x2 = fmaxf(x2, dpp_mov<C>(x2, x2)); x3 = fmaxf(x3, dpp_mov<C>(x3, x3));
        RSTEP(0xB1)   // quad_perm [1,0,3,2]
        RSTEP(0x4E)   // quad_perm [2,3,0,1]
        RSTEP(0x141)  // row_half_mirror
        RSTEP(0x140)  // row_mirror
        RSTEP(0x142)  // row_bcast15
        RSTEP(0x143)  // row_bcast31
        #undef RSTEP
        float S0 = __builtin_bit_cast(float, __builtin_amdgcn_readlane(__builtin_bit_cast(int, s0), 63));
        float S1 = __builtin_bit_cast(float, __builtin_amdgcn_readlane(__builtin_bit_cast(int, s1), 63));
        float S2 = __builtin_bit_cast(float, __builtin_amdgcn_readlane(__builtin_bit_cast(int, s2), 63));
        float S3 = __builtin_bit_cast(float, __builtin_amdgcn_readlane(__builtin_bit_cast(int, s3), 63));
        float X0 = __builtin_bit_cast(float, __builtin_amdgcn_readlane(__builtin_bit_cast(int, x0), 63));
        float X1 = __builtin_bit_cast(float, __builtin_amdgcn_readlane(__builtin_bit_cast(int, x1), 63));
        float X2 = __builtin_bit_cast(float, __builtin_amdgcn_readlane(__builtin_bit_cast(int, x2), 63));
        float X3 = __builtin_bit_cast(float, __builtin_amdgcn_readlane(__builtin_bit_cast(int, x3), 63));

        // fast path: w[255] true -> k_z = 255, m_z = full sum (~always for BN'd data)
        float t0 = (S0 + 1.0f) * (1.0f / 255.0f);
        float t1 = (S1 + 1.0f) * (1.0f / 255.0f);
        float t2 = (S2 + 1.0f) * (1.0f / 255.0f);
        float t3 = (S3 + 1.0f) * (1.0f / 255.0f);
        bool b0 = !(1.0f + 255.0f * X0 - S0 > 0.0f);
        bool b1 = !(1.0f + 255.0f * X1 - S1 > 0.0f);
        bool b2 = !(1.0f + 255.0f * X2 - S2 > 0.0f);
        bool b3 = !(1.0f + 255.0f * X3 - S3 > 0.0f);
        if (b0 | b1 | b2 | b3) {                   // wave-uniform (S,X are wave-uniform)
            float* sr = zrow[wid];
            if (b0) t0 = slow_tau(zr0[0], zr0[1], zr0[2], zr0[3], sr, lane);
            if (b1) t1 = slow_tau(zr1[0], zr1[1], zr1[2], zr1[3], sr, lane);
            if (b2) t2 = slow_tau(zr2[0], zr2[1], zr2[2], zr2[3], sr, lane);
            if (b3) t3 = slow_tau(zr3[0], zr3[1], zr3[2], zr3[3], sr, lane);
        }

        // outputs: m = relu(z - tau); new_prior = p * (1.5 - m)  (nontemporal stores)
        size_t gb = (rowbase + rg * 4) * F_ + 4 * lane;
        {
            float m0 = fmaxf(zr0[0] - t0, 0.f), m1 = fmaxf(zr0[1] - t0, 0.f);
            float m2 = fmaxf(zr0[2] - t0, 0.f), m3 = fmaxf(zr0[3] - t0, 0.f);
            ntstore4(out_m + gb, (float4){m0, m1, m2, m3});
            ntstore4(out_np + gb, (float4){pv0[0] * (GAMMA_ - m0), pv0[1] * (GAMMA_ - m1),
                                           pv0[2] * (GAMMA_ - m2), pv0[3] * (GAMMA_ - m3)});
        }
        {
            float m0 = fmaxf(zr1[0] - t1, 0.f), m1 = fmaxf(zr1[1] - t1, 0.f);
            float m2 = fmaxf(zr1[2] - t1, 0.f), m3 = fmaxf(zr1[3] - t1, 0.f);
            ntstore4(out_m + gb + F_, (float4){m0, m1, m2, m3});
            ntstore4(out_np + gb + F_, (float4){pv1[0] * (GAMMA_ - m0), pv1[1] * (GAMMA_ - m1),
                                                pv1[2] * (GAMMA_ - m2), pv1[3] * (GAMMA_ - m3)});
        }
        {
            float m0 = fmaxf(zr2[0] - t2, 0.f), m1 = fmaxf(zr2[1] - t2, 0.f);
            float m2 = fmaxf(zr2[2] - t2, 0.f), m3 = fmaxf(zr2[3] - t2, 0.f);
            ntstore4(out_m + gb + 2 * F_, (float4){m0, m1, m2, m3});
            ntstore4(out_np + gb + 2 * F_, (float4){pv2[0] * (GAMMA_ - m0), pv2[1] * (GAMMA_ - m1),
                                                    pv2[2] * (GAMMA_ - m2), pv2[3] * (GAMMA_ - m3)});
        }
        {
            float m0 = fmaxf(zr3[0] - t3, 0.f), m1 = fmaxf(zr3[1] - t3, 0.f);
            float m2 = fmaxf(zr3[2] - t3, 0.f), m3 = fmaxf(zr3[3] - t3, 0.f);
            ntstore4(out_m + gb + 3 * F_, (float4){m0, m1, m2, m3});
            ntstore4(out_np + gb + 3 * F_, (float4){pv3[0] * (GAMMA_ - m0), pv3[1] * (GAMMA_ - m1),
                                                    pv3[2] * (GAMMA_ - m2), pv3[3] * (GAMMA_ - m3)});
        }
    }
}

extern "C" void kernel_launch(void* const* d_in, const int* in_sizes, int n_in,
                              void* d_out, int out_size, void* d_ws, size_t ws_size,
                              hipStream_t stream) {
    const float* a     = (const float*)d_in[0];
    const float* prior = (const float*)d_in[1];
    const float* W     = (const float*)d_in[2];
    const float* bnw   = (const float*)d_in[4];
    const float* bnb   = (const float*)d_in[5];
    const int N = in_sizes[0] / NA_;
    const int nchunks = N / VBS_;
    float* out_m  = (float*)d_out;
    float* out_np = out_m + (size_t)N * F_;

    unsigned short* Wb = (unsigned short*)d_ws;    // 64 KB in workspace
    k0_cvt_w<<<(F_ * NA_ / 4 + 255) / 256, 256, 0, stream>>>(W, Wb);
    k_fused<<<nchunks, 512, 0, stream>>>(a, Wb, bnw, bnb, prior, out_m, out_np);
}